// Round 1
// baseline (3089.628 us; speedup 1.0000x reference)
//
#include <hip/hip_runtime.h>
#include <math.h>

#define B_SZ   2
#define L_SEQ  4096
#define DIMC   128
#define DI     256      // D_INNER
#define DST    16       // D_STATE
#define DTR    8        // DT_RANK
#define NXP    40       // DTR + 2*DST
#define NLAYER 8

__device__ __forceinline__ float silu_f(float x) { return x / (1.f + expf(-x)); }
__device__ __forceinline__ float softplus_f(float x) {
    return fmaxf(x, 0.f) + log1pf(expf(-fabsf(x)));
}

// ---------------- transpose (B,C,L) -> (B,L,C) ----------------
__global__ void transpose_in(const float* __restrict__ x, float* __restrict__ h) {
    __shared__ float tl[32][33];
    const int b  = blockIdx.x;
    const int c0 = blockIdx.y * 32;
    const int l0 = blockIdx.z * 32;
    const int tx = threadIdx.x;   // 0..31
    const int ty = threadIdx.y;   // 0..7
    #pragma unroll
    for (int r = 0; r < 4; ++r) {
        int c = c0 + ty + r * 8;
        tl[ty + r * 8][tx] = x[((size_t)b * DIMC + c) * L_SEQ + l0 + tx];
    }
    __syncthreads();
    #pragma unroll
    for (int r = 0; r < 4; ++r) {
        int l = l0 + ty + r * 8;
        h[((size_t)b * L_SEQ + l) * DIMC + c0 + tx] = tl[tx][ty + r * 8];
    }
}

// ---------------- generic C[M,N] = A[M,K] * W[N,K]^T ----------------
template<int BM, int BN, int BK>
__global__ void gemm_bt(const float* __restrict__ A, const float* __restrict__ W,
                        float* __restrict__ C, int M, int N, int K) {
    __shared__ float As[BK][BM + 1];
    __shared__ float Ws[BK][BN + 1];
    const int bm = blockIdx.x * BM;
    const int bn = blockIdx.y * BN;
    const int t  = threadIdx.x;            // 256 threads
    const int tx = t & 15, ty = t >> 4;    // 16x16
    float acc[4][4] = {};
    for (int k0 = 0; k0 < K; k0 += BK) {
        for (int i = t; i < BM * BK; i += 256) {
            int m = i / BK, kk = i % BK;
            As[kk][m] = A[(size_t)(bm + m) * K + k0 + kk];
        }
        for (int i = t; i < BN * BK; i += 256) {
            int n = i / BK, kk = i % BK;
            Ws[kk][n] = (bn + n < N) ? W[(size_t)(bn + n) * K + k0 + kk] : 0.f;
        }
        __syncthreads();
        #pragma unroll
        for (int kk = 0; kk < BK; ++kk) {
            float a[4], w[4];
            #pragma unroll
            for (int i = 0; i < 4; ++i) a[i] = As[kk][ty * 4 + i];
            #pragma unroll
            for (int j = 0; j < 4; ++j) w[j] = Ws[kk][tx * 4 + j];
            #pragma unroll
            for (int i = 0; i < 4; ++i)
                #pragma unroll
                for (int j = 0; j < 4; ++j) acc[i][j] += a[i] * w[j];
        }
        __syncthreads();
    }
    #pragma unroll
    for (int i = 0; i < 4; ++i) {
        int m = bm + ty * 4 + i;
        #pragma unroll
        for (int j = 0; j < 4; ++j) {
            int n = bn + tx * 4 + j;
            if (n < N) C[(size_t)m * N + n] = acc[i][j];
        }
    }
}

// ---------------- causal depthwise conv (D_CONV=4) + bias + silu ----------------
__global__ void conv_silu(const float* __restrict__ xz, const float* __restrict__ cw,
                          const float* __restrict__ cb, float* __restrict__ xc) {
    const int idx = blockIdx.x * 256 + threadIdx.x;   // over B*L*DI
    if (idx >= B_SZ * L_SEQ * DI) return;
    const int d = idx & (DI - 1);
    const int l = (idx >> 8) & (L_SEQ - 1);
    const int b = idx >> 20;
    float acc = cb[d];
    #pragma unroll
    for (int j = 0; j < 4; ++j) {
        int ll = l - 3 + j;
        if (ll >= 0)
            acc += cw[d * 4 + j] * xz[((size_t)b * L_SEQ + ll) * (2 * DI) + d];
    }
    xc[idx] = silu_f(acc);
}

// ---------------- dt_proj (K=8) + softplus ----------------
__global__ void dtproj(const float* __restrict__ xdbl, const float* __restrict__ dtw,
                       const float* __restrict__ dtb, float* __restrict__ delta) {
    const int idx = blockIdx.x * 256 + threadIdx.x;   // over B*L*DI
    if (idx >= B_SZ * L_SEQ * DI) return;
    const int d = idx & (DI - 1);
    const int m = idx >> 8;
    const float* row = xdbl + (size_t)m * NXP;
    const float* wr  = dtw + d * DTR;
    float s = dtb[d];
    #pragma unroll
    for (int r = 0; r < DTR; ++r) s += row[r] * wr[r];
    delta[idx] = softplus_f(s);
}

// ---------------- chunked selective scan + skip + silu(z) gate ----------------
__global__ void scan_gate(const float* __restrict__ delta, const float* __restrict__ xc,
                          const float* __restrict__ xdbl, const float* __restrict__ xz,
                          const float* __restrict__ A_log, const float* __restrict__ D_skip,
                          float* __restrict__ y) {
    const int blk = blockIdx.x;           // b*DI + d
    const int b = blk / DI, d = blk % DI;
    const int t = threadIdx.x;            // 256
    const int c = t >> 4, n = t & 15;     // chunk, state
    const int CS = L_SEQ / 16;            // 256
    __shared__ float paS[16][16], hS[16][16], hiS[16][16];
    const float An = -expf(A_log[d * DST + n]);
    const float Dd = D_skip[d];
    const int l0 = c * CS;
    // Phase A: per-chunk scan from zero init
    float pa = 1.f, h = 0.f;
    for (int i = 0; i < CS; ++i) {
        const size_t r = (size_t)b * L_SEQ + l0 + i;
        float dl = delta[r * DI + d];
        float ul = xc[r * DI + d];
        float Bn = xdbl[r * NXP + DTR + n];
        float dA = expf(dl * An);
        h = dA * h + dl * ul * Bn;
        pa *= dA;
    }
    paS[c][n] = pa; hS[c][n] = h;
    __syncthreads();
    // Phase B: combine chunk states (16 threads, one per state)
    if (t < 16) {
        float run = 0.f;
        hiS[0][t] = 0.f;
        for (int cc = 0; cc < 15; ++cc) {
            run = paS[cc][t] * run + hS[cc][t];
            hiS[cc + 1][t] = run;
        }
    }
    __syncthreads();
    // Phase C: recompute with correct init, produce gated y
    h = hiS[c][n];
    for (int i = 0; i < CS; ++i) {
        const size_t r = (size_t)b * L_SEQ + l0 + i;
        float dl = delta[r * DI + d];
        float ul = xc[r * DI + d];
        float Bn = xdbl[r * NXP + DTR + n];
        float Cn = xdbl[r * NXP + DTR + DST + n];
        float dA = expf(dl * An);
        h = dA * h + dl * ul * Bn;
        float yp = h * Cn;
        yp += __shfl_xor(yp, 1);
        yp += __shfl_xor(yp, 2);
        yp += __shfl_xor(yp, 4);
        yp += __shfl_xor(yp, 8);
        if (n == 0) {
            float zv = xz[r * (2 * DI) + DI + d];
            y[r * DI + d] = (yp + ul * Dd) * silu_f(zv);
        }
    }
}

// ---------------- RMSNorm over C=128 + transpose (B,L,C) -> (B,C,L) ----------------
__global__ void rms_out(const float* __restrict__ h, const float* __restrict__ rw,
                        float* __restrict__ out) {
    __shared__ float tile[64][129];
    __shared__ float rinv[64];
    const int blk = blockIdx.x;           // b*(L/64) + l-block
    const int b = blk / (L_SEQ / 64);
    const int l0 = (blk % (L_SEQ / 64)) * 64;
    const int t = threadIdx.x;            // 256
    for (int k = 0; k < 32; ++k) {
        int idx = k * 256 + t;
        int l = idx >> 7, cc = idx & 127;
        tile[l][cc] = h[((size_t)b * L_SEQ + l0 + l) * DIMC + cc];
    }
    __syncthreads();
    if (t < 64) {
        float s = 0.f;
        for (int cc = 0; cc < DIMC; ++cc) { float v = tile[t][cc]; s += v * v; }
        rinv[t] = rsqrtf(s / DIMC + 1e-6f);
    }
    __syncthreads();
    for (int k = 0; k < 32; ++k) {
        int odx = k * 256 + t;
        int cc = odx >> 6, li = odx & 63;
        out[((size_t)b * DIMC + cc) * L_SEQ + l0 + li] = tile[li][cc] * rinv[li] * rw[cc];
    }
}

extern "C" void kernel_launch(void* const* d_in, const int* in_sizes, int n_in,
                              void* d_out, int out_size, void* d_ws, size_t ws_size,
                              hipStream_t stream) {
    const float* x      = (const float*)d_in[0];
    const float* in_w   = (const float*)d_in[1];
    const float* conv_w = (const float*)d_in[2];
    const float* conv_b = (const float*)d_in[3];
    const float* xp_w   = (const float*)d_in[4];
    const float* dt_w   = (const float*)d_in[5];
    const float* dt_b   = (const float*)d_in[6];
    const float* A_log  = (const float*)d_in[7];
    const float* D_skip = (const float*)d_in[8];
    const float* out_w  = (const float*)d_in[9];
    const float* rms_w  = (const float*)d_in[10];
    float* out = (float*)d_out;

    const int M = B_SZ * L_SEQ;   // 8192
    float* ws   = (float*)d_ws;
    float* h0   = ws;                       // M*128
    float* h1   = h0 + (size_t)M * DIMC;    // M*128
    float* xz   = h1 + (size_t)M * DIMC;    // M*512
    float* xc   = xz + (size_t)M * 2 * DI;  // M*256
    float* xdbl = xc + (size_t)M * DI;      // M*40
    float* dlt  = xdbl + (size_t)M * NXP;   // M*256
    float* yb   = dlt + (size_t)M * DI;     // M*256

    // x (B,C,L) -> h0 (B,L,C)
    transpose_in<<<dim3(B_SZ, DIMC / 32, L_SEQ / 32), dim3(32, 8), 0, stream>>>(x, h0);

    float* hin = h0;
    float* hout = h1;
    for (int layer = 0; layer < NLAYER; ++layer) {
        const float* iw  = in_w   + (size_t)layer * 2 * DI * DIMC;
        const float* cw  = conv_w + (size_t)layer * DI * 4;
        const float* cb  = conv_b + (size_t)layer * DI;
        const float* xpw = xp_w   + (size_t)layer * NXP * DI;
        const float* dtw = dt_w   + (size_t)layer * DI * DTR;
        const float* dtb = dt_b   + (size_t)layer * DI;
        const float* al  = A_log  + (size_t)layer * DI * DST;
        const float* ds  = D_skip + (size_t)layer * DI;
        const float* ow  = out_w  + (size_t)layer * DIMC * DI;

        // in_proj: xz = hin * iw^T   (M x 512, K=128)
        gemm_bt<64, 64, 16><<<dim3(M / 64, (2 * DI) / 64), 256, 0, stream>>>(
            hin, iw, xz, M, 2 * DI, DIMC);
        // conv + silu -> xc
        conv_silu<<<(M * DI) / 256, 256, 0, stream>>>(xz, cw, cb, xc);
        // x_proj: xdbl = xc * xpw^T  (M x 40, K=256)
        gemm_bt<64, 64, 16><<<dim3(M / 64, 1), 256, 0, stream>>>(
            xc, xpw, xdbl, M, NXP, DI);
        // dt_proj + softplus -> delta
        dtproj<<<(M * DI) / 256, 256, 0, stream>>>(xdbl, dtw, dtb, dlt);
        // selective scan + gate -> yb
        scan_gate<<<B_SZ * DI, 256, 0, stream>>>(dlt, xc, xdbl, xz, al, ds, yb);
        // out_proj: hout = yb * ow^T (M x 128, K=256)
        gemm_bt<64, 64, 16><<<dim3(M / 64, DIMC / 64), 256, 0, stream>>>(
            yb, ow, hout, M, DIMC, DI);

        float* tmp = hin; hin = hout; hout = tmp;
    }

    // RMSNorm + transpose to (B,C,H,W)
    rms_out<<<B_SZ * (L_SEQ / 64), 256, 0, stream>>>(hin, rms_w, out);
}

// Round 2
// 1557.462 us; speedup vs baseline: 1.9838x; 1.9838x over previous
//
#include <hip/hip_runtime.h>
#include <math.h>

#define B_SZ   2
#define L_SEQ  4096
#define DIMC   128
#define DI     256      // D_INNER
#define DST    16       // D_STATE
#define DTR    8        // DT_RANK
#define NXP    40       // DTR + 2*DST
#define NLAYER 8
#define NCH    128      // chunks per batch
#define CS     (L_SEQ / NCH)   // 32 steps per chunk
#define LOG2E  1.4426950408889634f

__device__ __forceinline__ float silu_f(float x) { return x / (1.f + expf(-x)); }
__device__ __forceinline__ float softplus_f(float x) {
    return fmaxf(x, 0.f) + log1pf(expf(-fabsf(x)));
}

// ---------------- transpose (B,C,L) -> (B,L,C) ----------------
__global__ void transpose_in(const float* __restrict__ x, float* __restrict__ h) {
    __shared__ float tl[32][33];
    const int b  = blockIdx.x;
    const int c0 = blockIdx.y * 32;
    const int l0 = blockIdx.z * 32;
    const int tx = threadIdx.x;   // 0..31
    const int ty = threadIdx.y;   // 0..7
    #pragma unroll
    for (int r = 0; r < 4; ++r) {
        int c = c0 + ty + r * 8;
        tl[ty + r * 8][tx] = x[((size_t)b * DIMC + c) * L_SEQ + l0 + tx];
    }
    __syncthreads();
    #pragma unroll
    for (int r = 0; r < 4; ++r) {
        int l = l0 + ty + r * 8;
        h[((size_t)b * L_SEQ + l) * DIMC + c0 + tx] = tl[tx][ty + r * 8];
    }
}

// ---------------- generic C[M,N] = A[M,K] * W[N,K]^T ----------------
template<int BM, int BN, int BK>
__global__ void gemm_bt(const float* __restrict__ A, const float* __restrict__ W,
                        float* __restrict__ C, int M, int N, int K) {
    __shared__ float As[BK][BM + 1];
    __shared__ float Ws[BK][BN + 1];
    const int bm = blockIdx.x * BM;
    const int bn = blockIdx.y * BN;
    const int t  = threadIdx.x;            // 256 threads
    const int tx = t & 15, ty = t >> 4;    // 16x16
    float acc[4][4] = {};
    for (int k0 = 0; k0 < K; k0 += BK) {
        for (int i = t; i < BM * BK; i += 256) {
            int m = i / BK, kk = i % BK;
            As[kk][m] = A[(size_t)(bm + m) * K + k0 + kk];
        }
        for (int i = t; i < BN * BK; i += 256) {
            int n = i / BK, kk = i % BK;
            Ws[kk][n] = (bn + n < N) ? W[(size_t)(bn + n) * K + k0 + kk] : 0.f;
        }
        __syncthreads();
        #pragma unroll
        for (int kk = 0; kk < BK; ++kk) {
            float a[4], w[4];
            #pragma unroll
            for (int i = 0; i < 4; ++i) a[i] = As[kk][ty * 4 + i];
            #pragma unroll
            for (int j = 0; j < 4; ++j) w[j] = Ws[kk][tx * 4 + j];
            #pragma unroll
            for (int i = 0; i < 4; ++i)
                #pragma unroll
                for (int j = 0; j < 4; ++j) acc[i][j] += a[i] * w[j];
        }
        __syncthreads();
    }
    #pragma unroll
    for (int i = 0; i < 4; ++i) {
        int m = bm + ty * 4 + i;
        #pragma unroll
        for (int j = 0; j < 4; ++j) {
            int n = bn + tx * 4 + j;
            if (n < N) C[(size_t)m * N + n] = acc[i][j];
        }
    }
}

// ---------------- causal depthwise conv (D_CONV=4) + bias + silu ----------------
__global__ void conv_silu(const float* __restrict__ xz, const float* __restrict__ cw,
                          const float* __restrict__ cb, float* __restrict__ xc) {
    const int idx = blockIdx.x * 256 + threadIdx.x;   // over B*L*DI
    if (idx >= B_SZ * L_SEQ * DI) return;
    const int d = idx & (DI - 1);
    const int l = (idx >> 8) & (L_SEQ - 1);
    const int b = idx >> 20;
    float acc = cb[d];
    #pragma unroll
    for (int j = 0; j < 4; ++j) {
        int ll = l - 3 + j;
        if (ll >= 0)
            acc += cw[d * 4 + j] * xz[((size_t)b * L_SEQ + ll) * (2 * DI) + d];
    }
    xc[idx] = silu_f(acc);
}

// ---------------- dt_proj (K=8) + softplus ----------------
__global__ void dtproj(const float* __restrict__ xdbl, const float* __restrict__ dtw,
                       const float* __restrict__ dtb, float* __restrict__ delta) {
    const int idx = blockIdx.x * 256 + threadIdx.x;   // over B*L*DI
    if (idx >= B_SZ * L_SEQ * DI) return;
    const int d = idx & (DI - 1);
    const int m = idx >> 8;
    const float* row = xdbl + (size_t)m * NXP;
    const float* wr  = dtw + d * DTR;
    float s = dtb[d];
    #pragma unroll
    for (int r = 0; r < DTR; ++r) s += row[r] * wr[r];
    delta[idx] = softplus_f(s);
}

// ---------------- Phase A: per-chunk scan from zero init (d-coalesced) ----------------
__global__ void scan_chunkA(const float* __restrict__ delta, const float* __restrict__ xc,
                            const float* __restrict__ xdbl, const float* __restrict__ A_log,
                            float* __restrict__ paO, float* __restrict__ hO) {
    const int b  = blockIdx.x >> 7;          // blockIdx.x = b*NCH + ch
    const int ch = blockIdx.x & (NCH - 1);
    const int d  = threadIdx.x;              // 0..255
    __shared__ float Bs[CS][DST];
    const size_t r0 = (size_t)b * L_SEQ + ch * CS;
    for (int idx = threadIdx.x; idx < CS * DST; idx += 256) {
        int i = idx >> 4, n = idx & 15;
        Bs[i][n] = xdbl[(r0 + i) * NXP + DTR + n];
    }
    float Af[DST], h[DST], pa[DST];
    #pragma unroll
    for (int n = 0; n < DST; ++n) {
        Af[n] = -expf(A_log[d * DST + n]) * LOG2E;
        h[n] = 0.f; pa[n] = 1.f;
    }
    __syncthreads();
    for (int i = 0; i < CS; ++i) {
        float dl = delta[(r0 + i) * DI + d];
        float ul = xc[(r0 + i) * DI + d];
        float du = dl * ul;
        #pragma unroll
        for (int n = 0; n < DST; ++n) {
            float dA = exp2f(dl * Af[n]);
            pa[n] *= dA;
            h[n] = fmaf(dA, h[n], du * Bs[i][n]);
        }
    }
    const size_t o = ((size_t)blockIdx.x * DI + d) * DST;
    #pragma unroll
    for (int n = 0; n < DST; ++n) { paO[o + n] = pa[n]; hO[o + n] = h[n]; }
}

// ---------------- Phase B: combine chunk states; paO becomes exclusive init ----------------
__global__ void scan_combine(float* __restrict__ paO, const float* __restrict__ hO) {
    const int t  = blockIdx.x * 256 + threadIdx.x;   // over B*DI*DST = 8192
    const int b  = t / (DI * DST);
    const int dn = t % (DI * DST);
    float run = 0.f;
    for (int ch0 = 0; ch0 < NCH; ch0 += 8) {
        float pav[8], hv[8];
        #pragma unroll
        for (int j = 0; j < 8; ++j) {
            size_t o = ((size_t)(b * NCH + ch0 + j)) * DI * DST + dn;
            pav[j] = paO[o]; hv[j] = hO[o];
        }
        #pragma unroll
        for (int j = 0; j < 8; ++j) {
            size_t o = ((size_t)(b * NCH + ch0 + j)) * DI * DST + dn;
            paO[o] = run;                    // exclusive prefix = chunk init state
            run = fmaf(pav[j], run, hv[j]);
        }
    }
}

// ---------------- Phase C: scan with init + skip + silu(z) gate ----------------
__global__ void scan_applyC(const float* __restrict__ delta, const float* __restrict__ xc,
                            const float* __restrict__ xdbl, const float* __restrict__ xz,
                            const float* __restrict__ A_log, const float* __restrict__ D_skip,
                            const float* __restrict__ hinit, float* __restrict__ y) {
    const int b  = blockIdx.x >> 7;
    const int ch = blockIdx.x & (NCH - 1);
    const int d  = threadIdx.x;
    __shared__ float Bs[CS][DST], Cs[CS][DST];
    const size_t r0 = (size_t)b * L_SEQ + ch * CS;
    for (int idx = threadIdx.x; idx < CS * 2 * DST; idx += 256) {
        int i = idx >> 5, c = idx & 31;
        float v = xdbl[(r0 + i) * NXP + DTR + c];
        if (c < DST) Bs[i][c] = v; else Cs[i][c - DST] = v;
    }
    float Af[DST], h[DST];
    const size_t o = ((size_t)blockIdx.x * DI + d) * DST;
    #pragma unroll
    for (int n = 0; n < DST; ++n) {
        Af[n] = -expf(A_log[d * DST + n]) * LOG2E;
        h[n] = hinit[o + n];
    }
    const float Dd = D_skip[d];
    __syncthreads();
    for (int i = 0; i < CS; ++i) {
        float dl = delta[(r0 + i) * DI + d];
        float ul = xc[(r0 + i) * DI + d];
        float zv = xz[(r0 + i) * 2 * DI + DI + d];
        float du = dl * ul;
        float acc = 0.f;
        #pragma unroll
        for (int n = 0; n < DST; ++n) {
            float dA = exp2f(dl * Af[n]);
            h[n] = fmaf(dA, h[n], du * Bs[i][n]);
            acc = fmaf(h[n], Cs[i][n], acc);
        }
        y[(r0 + i) * DI + d] = (acc + ul * Dd) * silu_f(zv);
    }
}

// ---------------- RMSNorm over C=128 + transpose (B,L,C) -> (B,C,L) ----------------
__global__ void rms_out(const float* __restrict__ h, const float* __restrict__ rw,
                        float* __restrict__ out) {
    __shared__ float tile[64][129];
    __shared__ float rinv[64];
    const int blk = blockIdx.x;           // b*(L/64) + l-block
    const int b = blk / (L_SEQ / 64);
    const int l0 = (blk % (L_SEQ / 64)) * 64;
    const int t = threadIdx.x;            // 256
    for (int k = 0; k < 32; ++k) {
        int idx = k * 256 + t;
        int l = idx >> 7, cc = idx & 127;
        tile[l][cc] = h[((size_t)b * L_SEQ + l0 + l) * DIMC + cc];
    }
    __syncthreads();
    if (t < 64) {
        float s = 0.f;
        for (int cc = 0; cc < DIMC; ++cc) { float v = tile[t][cc]; s += v * v; }
        rinv[t] = rsqrtf(s / DIMC + 1e-6f);
    }
    __syncthreads();
    for (int k = 0; k < 32; ++k) {
        int odx = k * 256 + t;
        int cc = odx >> 6, li = odx & 63;
        out[((size_t)b * DIMC + cc) * L_SEQ + l0 + li] = tile[li][cc] * rinv[li] * rw[cc];
    }
}

extern "C" void kernel_launch(void* const* d_in, const int* in_sizes, int n_in,
                              void* d_out, int out_size, void* d_ws, size_t ws_size,
                              hipStream_t stream) {
    const float* x      = (const float*)d_in[0];
    const float* in_w   = (const float*)d_in[1];
    const float* conv_w = (const float*)d_in[2];
    const float* conv_b = (const float*)d_in[3];
    const float* xp_w   = (const float*)d_in[4];
    const float* dt_w   = (const float*)d_in[5];
    const float* dt_b   = (const float*)d_in[6];
    const float* A_log  = (const float*)d_in[7];
    const float* D_skip = (const float*)d_in[8];
    const float* out_w  = (const float*)d_in[9];
    const float* rms_w  = (const float*)d_in[10];
    float* out = (float*)d_out;

    const int M = B_SZ * L_SEQ;   // 8192
    float* ws   = (float*)d_ws;
    float* h0   = ws;                       // M*128
    float* h1   = h0 + (size_t)M * DIMC;    // M*128
    float* xz   = h1 + (size_t)M * DIMC;    // M*512
    float* xc   = xz + (size_t)M * 2 * DI;  // M*256
    float* xdbl = xc + (size_t)M * DI;      // M*40
    float* dlt  = xdbl + (size_t)M * NXP;   // M*256
    float* yb   = dlt + (size_t)M * DI;     // M*256
    float* paB  = yb + (size_t)M * DI;                       // B*NCH*DI*DST
    float* hB   = paB + (size_t)B_SZ * NCH * DI * DST;       // B*NCH*DI*DST

    // x (B,C,L) -> h0 (B,L,C)
    transpose_in<<<dim3(B_SZ, DIMC / 32, L_SEQ / 32), dim3(32, 8), 0, stream>>>(x, h0);

    float* hin = h0;
    float* hout = h1;
    for (int layer = 0; layer < NLAYER; ++layer) {
        const float* iw  = in_w   + (size_t)layer * 2 * DI * DIMC;
        const float* cw  = conv_w + (size_t)layer * DI * 4;
        const float* cb  = conv_b + (size_t)layer * DI;
        const float* xpw = xp_w   + (size_t)layer * NXP * DI;
        const float* dtw = dt_w   + (size_t)layer * DI * DTR;
        const float* dtb = dt_b   + (size_t)layer * DI;
        const float* al  = A_log  + (size_t)layer * DI * DST;
        const float* ds  = D_skip + (size_t)layer * DI;
        const float* ow  = out_w  + (size_t)layer * DIMC * DI;

        // in_proj: xz = hin * iw^T   (M x 512, K=128)
        gemm_bt<64, 64, 16><<<dim3(M / 64, (2 * DI) / 64), 256, 0, stream>>>(
            hin, iw, xz, M, 2 * DI, DIMC);
        // conv + silu -> xc
        conv_silu<<<(M * DI) / 256, 256, 0, stream>>>(xz, cw, cb, xc);
        // x_proj: xdbl = xc * xpw^T  (M x 40, K=256)
        gemm_bt<64, 64, 16><<<dim3(M / 64, 1), 256, 0, stream>>>(
            xc, xpw, xdbl, M, NXP, DI);
        // dt_proj + softplus -> delta
        dtproj<<<(M * DI) / 256, 256, 0, stream>>>(xdbl, dtw, dtb, dlt);
        // chunked selective scan (3 phases) + gate -> yb
        scan_chunkA<<<B_SZ * NCH, 256, 0, stream>>>(dlt, xc, xdbl, al, paB, hB);
        scan_combine<<<(B_SZ * DI * DST) / 256, 256, 0, stream>>>(paB, hB);
        scan_applyC<<<B_SZ * NCH, 256, 0, stream>>>(dlt, xc, xdbl, xz, al, ds, paB, yb);
        // out_proj: hout = yb * ow^T (M x 128, K=256)
        gemm_bt<64, 64, 16><<<dim3(M / 64, DIMC / 64), 256, 0, stream>>>(
            yb, ow, hout, M, DIMC, DI);

        float* tmp = hin; hin = hout; hout = tmp;
    }

    // RMSNorm + transpose to (B,C,H,W)
    rms_out<<<B_SZ * (L_SEQ / 64), 256, 0, stream>>>(hin, rms_w, out);
}

// Round 3
// 985.629 us; speedup vs baseline: 3.1347x; 1.5802x over previous
//
#include <hip/hip_runtime.h>
#include <math.h>

#define B_SZ   2
#define L_SEQ  4096
#define DIMC   128
#define DI     256      // D_INNER
#define DST    16       // D_STATE
#define DTR    8        // DT_RANK
#define NXP    40       // DTR + 2*DST
#define NLAYER 8
#define NCH    128      // chunks per batch
#define CS     (L_SEQ / NCH)   // 32 steps per chunk
#define LOG2E  1.4426950408889634f

typedef __attribute__((ext_vector_type(8))) unsigned short u16x8;
typedef __attribute__((ext_vector_type(4))) float f32x4;

__device__ __forceinline__ float silu_f(float x) { return x / (1.f + expf(-x)); }
__device__ __forceinline__ float softplus_f(float x) {
    return fmaxf(x, 0.f) + log1pf(expf(-fabsf(x)));
}
// split fp32 -> bf16 hi + bf16 lo (2-term), truncation-based
__device__ __forceinline__ void splitf(float x, unsigned short& h, unsigned short& l) {
    unsigned bx = __builtin_bit_cast(unsigned, x);
    h = (unsigned short)(bx >> 16);
    float fh = __builtin_bit_cast(float, bx & 0xffff0000u);
    float r = x - fh;
    l = (unsigned short)(__builtin_bit_cast(unsigned, r) >> 16);
}

// ---------------- split a weight tensor into bf16 hi/lo ----------------
__global__ void split_arr(const float* __restrict__ s, unsigned short* __restrict__ hi,
                          unsigned short* __restrict__ lo, int n) {
    int i = (blockIdx.x * 256 + threadIdx.x) * 4;
    if (i >= n) return;
    #pragma unroll
    for (int j = 0; j < 4; ++j) {
        unsigned short h, l;
        splitf(s[i + j], h, l);
        hi[i + j] = h; lo[i + j] = l;
    }
}

// ---------------- transpose (B,C,L) -> (B,L,C), emit split bf16 ----------------
__global__ void transpose_in(const float* __restrict__ x, unsigned short* __restrict__ hh,
                             unsigned short* __restrict__ hl) {
    __shared__ float tl[32][33];
    const int b  = blockIdx.x;
    const int c0 = blockIdx.y * 32;
    const int l0 = blockIdx.z * 32;
    const int tx = threadIdx.x;   // 0..31
    const int ty = threadIdx.y;   // 0..7
    #pragma unroll
    for (int r = 0; r < 4; ++r) {
        int c = c0 + ty + r * 8;
        tl[ty + r * 8][tx] = x[((size_t)b * DIMC + c) * L_SEQ + l0 + tx];
    }
    __syncthreads();
    #pragma unroll
    for (int r = 0; r < 4; ++r) {
        int l = l0 + ty + r * 8;
        float v = tl[tx][ty + r * 8];
        size_t o = ((size_t)b * L_SEQ + l) * DIMC + c0 + tx;
        unsigned short h16, l16; splitf(v, h16, l16);
        hh[o] = h16; hl[o] = l16;
    }
}

// ---------------- MFMA GEMM: C[M,N] = A[M,K] * W[N,K]^T  (split-bf16, 3-pass) ----------------
// A, W pre-split into bf16 hi/lo (row-major [rows][K]).
template<int BM, int BN, bool SOUT>
__global__ __launch_bounds__(256) void gemm_sp(
    const unsigned short* __restrict__ Ahg, const unsigned short* __restrict__ Alg,
    const unsigned short* __restrict__ Whg, const unsigned short* __restrict__ Wlg,
    float* __restrict__ C, unsigned short* __restrict__ Ch, unsigned short* __restrict__ Cl,
    int M, int N, int K) {
    constexpr int PS = 40;          // padded LDS row stride in bf16 (80B -> conflict-free)
    __shared__ unsigned short lds[(BM + BN) * 2 * PS];
    unsigned short* LAh = lds;
    unsigned short* LAl = LAh + BM * PS;
    unsigned short* LBh = LAl + BM * PS;
    unsigned short* LBl = LBh + BN * PS;
    const int t = threadIdx.x;
    const int w = t >> 6, l = t & 63;
    const int wr = w >> 1, wc = w & 1;        // 2x2 waves over the tile
    const int lr = l & 15, lq = l >> 4;       // lane row (0..15), k-quad (0..3)
    constexpr int MF = BM / 32, NF = BN / 32; // 16x16 frags per wave
    const int bm = blockIdx.x * BM, bn = blockIdx.y * BN;
    f32x4 acc[MF][NF];
    const f32x4 z4 = {0.f, 0.f, 0.f, 0.f};
    #pragma unroll
    for (int m = 0; m < MF; ++m)
        #pragma unroll
        for (int n = 0; n < NF; ++n) acc[m][n] = z4;

    for (int k0 = 0; k0 < K; k0 += 32) {
        if (k0) __syncthreads();
        #pragma unroll
        for (int s = 0; s < BM * 4 / 256; ++s) {
            int task = t + s * 256;
            int r = task >> 2, g = task & 3;
            size_t go = (size_t)(bm + r) * K + k0 + g * 8;
            *(u16x8*)&LAh[r * PS + g * 8] = *(const u16x8*)&Ahg[go];
            *(u16x8*)&LAl[r * PS + g * 8] = *(const u16x8*)&Alg[go];
        }
        #pragma unroll
        for (int s = 0; s < BN * 4 / 256; ++s) {
            int task = t + s * 256;
            int r = task >> 2, g = task & 3;
            u16x8 vh = {0,0,0,0,0,0,0,0}, vl = {0,0,0,0,0,0,0,0};
            if (bn + r < N) {
                size_t go = (size_t)(bn + r) * K + k0 + g * 8;
                vh = *(const u16x8*)&Whg[go];
                vl = *(const u16x8*)&Wlg[go];
            }
            *(u16x8*)&LBh[r * PS + g * 8] = vh;
            *(u16x8*)&LBl[r * PS + g * 8] = vl;
        }
        __syncthreads();
        u16x8 ah[MF], al[MF], bh[NF], bl[NF];
        #pragma unroll
        for (int m = 0; m < MF; ++m) {
            int rr = wr * (BM / 2) + m * 16 + lr;
            ah[m] = *(u16x8*)&LAh[rr * PS + lq * 8];
            al[m] = *(u16x8*)&LAl[rr * PS + lq * 8];
        }
        #pragma unroll
        for (int n = 0; n < NF; ++n) {
            int rr = wc * (BN / 2) + n * 16 + lr;
            bh[n] = *(u16x8*)&LBh[rr * PS + lq * 8];
            bl[n] = *(u16x8*)&LBl[rr * PS + lq * 8];
        }
        #pragma unroll
        for (int m = 0; m < MF; ++m)
            #pragma unroll
            for (int n = 0; n < NF; ++n) {
                asm("v_mfma_f32_16x16x32_bf16 %0, %1, %2, %0" : "+v"(acc[m][n]) : "v"(ah[m]), "v"(bh[n]));
                asm("v_mfma_f32_16x16x32_bf16 %0, %1, %2, %0" : "+v"(acc[m][n]) : "v"(ah[m]), "v"(bl[n]));
                asm("v_mfma_f32_16x16x32_bf16 %0, %1, %2, %0" : "+v"(acc[m][n]) : "v"(al[m]), "v"(bh[n]));
            }
    }
    #pragma unroll
    for (int m = 0; m < MF; ++m) {
        #pragma unroll
        for (int n = 0; n < NF; ++n) {
            int col = bn + wc * (BN / 2) + n * 16 + lr;
            if (col < N) {
                #pragma unroll
                for (int r = 0; r < 4; ++r) {
                    int row = bm + wr * (BM / 2) + m * 16 + lq * 4 + r;
                    float v = acc[m][n][r];
                    C[(size_t)row * N + col] = v;
                    if constexpr (SOUT) {
                        unsigned short h16, l16; splitf(v, h16, l16);
                        Ch[(size_t)row * N + col] = h16;
                        Cl[(size_t)row * N + col] = l16;
                    }
                }
            }
        }
    }
}

// ---------------- causal depthwise conv (D_CONV=4) + bias + silu (+ split out) ----------------
__global__ void conv_silu(const float* __restrict__ xz, const float* __restrict__ cw,
                          const float* __restrict__ cb, float* __restrict__ xc,
                          unsigned short* __restrict__ xch, unsigned short* __restrict__ xcl) {
    const int idx = blockIdx.x * 256 + threadIdx.x;   // over B*L*DI
    if (idx >= B_SZ * L_SEQ * DI) return;
    const int d = idx & (DI - 1);
    const int l = (idx >> 8) & (L_SEQ - 1);
    const int b = idx >> 20;
    float acc = cb[d];
    #pragma unroll
    for (int j = 0; j < 4; ++j) {
        int ll = l - 3 + j;
        if (ll >= 0)
            acc += cw[d * 4 + j] * xz[((size_t)b * L_SEQ + ll) * (2 * DI) + d];
    }
    float v = silu_f(acc);
    xc[idx] = v;
    unsigned short h16, l16; splitf(v, h16, l16);
    xch[idx] = h16; xcl[idx] = l16;
}

// ---------------- Phase A: per-chunk scan from zero init (dt fused) ----------------
__global__ void scan_chunkA(const float* __restrict__ xdbl, const float* __restrict__ xc,
                            const float* __restrict__ dtw, const float* __restrict__ dtb,
                            const float* __restrict__ A_log,
                            float* __restrict__ paO, float* __restrict__ hO) {
    const int b  = blockIdx.x >> 7;
    const int ch = blockIdx.x & (NCH - 1);
    const int d  = threadIdx.x;              // 0..255
    __shared__ float Ss[CS][NXP];            // 32 x 40 (dt|B|C rows)
    const size_t r0 = (size_t)b * L_SEQ + ch * CS;
    const float* src = xdbl + r0 * NXP;
    for (int idx = threadIdx.x; idx < CS * NXP; idx += 256)
        ((float*)Ss)[idx] = src[idx];
    float wt[DTR];
    #pragma unroll
    for (int r = 0; r < DTR; ++r) wt[r] = dtw[d * DTR + r];
    const float bt = dtb[d];
    float Af[DST], h[DST], pa[DST];
    #pragma unroll
    for (int n = 0; n < DST; ++n) {
        Af[n] = -expf(A_log[d * DST + n]) * LOG2E;
        h[n] = 0.f; pa[n] = 1.f;
    }
    __syncthreads();
    for (int i = 0; i < CS; ++i) {
        float s = bt;
        #pragma unroll
        for (int r = 0; r < DTR; ++r) s = fmaf(Ss[i][r], wt[r], s);
        float dl = softplus_f(s);
        float ul = xc[(r0 + i) * DI + d];
        float du = dl * ul;
        #pragma unroll
        for (int n = 0; n < DST; ++n) {
            float dA = exp2f(dl * Af[n]);
            pa[n] *= dA;
            h[n] = fmaf(dA, h[n], du * Ss[i][DTR + n]);
        }
    }
    const size_t o = ((size_t)blockIdx.x * DI + d) * DST;
    #pragma unroll
    for (int n = 0; n < DST; ++n) { paO[o + n] = pa[n]; hO[o + n] = h[n]; }
}

// ---------------- Phase B: combine chunk states; paO becomes exclusive init ----------------
__global__ void scan_combine(float* __restrict__ paO, const float* __restrict__ hO) {
    const int t  = blockIdx.x * 256 + threadIdx.x;   // over B*DI*DST = 8192
    const int b  = t / (DI * DST);
    const int dn = t % (DI * DST);
    float run = 0.f;
    for (int ch0 = 0; ch0 < NCH; ch0 += 8) {
        float pav[8], hv[8];
        #pragma unroll
        for (int j = 0; j < 8; ++j) {
            size_t o = ((size_t)(b * NCH + ch0 + j)) * DI * DST + dn;
            pav[j] = paO[o]; hv[j] = hO[o];
        }
        #pragma unroll
        for (int j = 0; j < 8; ++j) {
            size_t o = ((size_t)(b * NCH + ch0 + j)) * DI * DST + dn;
            paO[o] = run;
            run = fmaf(pav[j], run, hv[j]);
        }
    }
}

// ---------------- Phase C: scan with init + skip + silu(z) gate, split-bf16 out ----------------
__global__ void scan_applyC(const float* __restrict__ xdbl, const float* __restrict__ xc,
                            const float* __restrict__ xz,
                            const float* __restrict__ dtw, const float* __restrict__ dtb,
                            const float* __restrict__ A_log, const float* __restrict__ D_skip,
                            const float* __restrict__ hinit,
                            unsigned short* __restrict__ ybh, unsigned short* __restrict__ ybl) {
    const int b  = blockIdx.x >> 7;
    const int ch = blockIdx.x & (NCH - 1);
    const int d  = threadIdx.x;
    __shared__ float Ss[CS][NXP];
    const size_t r0 = (size_t)b * L_SEQ + ch * CS;
    const float* src = xdbl + r0 * NXP;
    for (int idx = threadIdx.x; idx < CS * NXP; idx += 256)
        ((float*)Ss)[idx] = src[idx];
    float wt[DTR];
    #pragma unroll
    for (int r = 0; r < DTR; ++r) wt[r] = dtw[d * DTR + r];
    const float bt = dtb[d];
    float Af[DST], h[DST];
    const size_t o = ((size_t)blockIdx.x * DI + d) * DST;
    #pragma unroll
    for (int n = 0; n < DST; ++n) {
        Af[n] = -expf(A_log[d * DST + n]) * LOG2E;
        h[n] = hinit[o + n];
    }
    const float Dd = D_skip[d];
    __syncthreads();
    for (int i = 0; i < CS; ++i) {
        float s = bt;
        #pragma unroll
        for (int r = 0; r < DTR; ++r) s = fmaf(Ss[i][r], wt[r], s);
        float dl = softplus_f(s);
        float ul = xc[(r0 + i) * DI + d];
        float zv = xz[(r0 + i) * 2 * DI + DI + d];
        float du = dl * ul;
        float acc = 0.f;
        #pragma unroll
        for (int n = 0; n < DST; ++n) {
            float dA = exp2f(dl * Af[n]);
            h[n] = fmaf(dA, h[n], du * Ss[i][DTR + n]);
            acc = fmaf(h[n], Ss[i][DTR + DST + n], acc);
        }
        float g = (acc + ul * Dd) * silu_f(zv);
        unsigned short h16, l16; splitf(g, h16, l16);
        ybh[(r0 + i) * DI + d] = h16;
        ybl[(r0 + i) * DI + d] = l16;
    }
}

// ---------------- RMSNorm over C=128 + transpose (B,L,C) -> (B,C,L) ----------------
__global__ void rms_out(const float* __restrict__ h, const float* __restrict__ rw,
                        float* __restrict__ out) {
    __shared__ float tile[64][129];
    __shared__ float rinv[64];
    const int blk = blockIdx.x;
    const int b = blk / (L_SEQ / 64);
    const int l0 = (blk % (L_SEQ / 64)) * 64;
    const int t = threadIdx.x;
    for (int k = 0; k < 32; ++k) {
        int idx = k * 256 + t;
        int l = idx >> 7, cc = idx & 127;
        tile[l][cc] = h[((size_t)b * L_SEQ + l0 + l) * DIMC + cc];
    }
    __syncthreads();
    if (t < 64) {
        float s = 0.f;
        for (int cc = 0; cc < DIMC; ++cc) { float v = tile[t][cc]; s += v * v; }
        rinv[t] = rsqrtf(s / DIMC + 1e-6f);
    }
    __syncthreads();
    for (int k = 0; k < 32; ++k) {
        int odx = k * 256 + t;
        int cc = odx >> 6, li = odx & 63;
        out[((size_t)b * DIMC + cc) * L_SEQ + l0 + li] = tile[li][cc] * rinv[li] * rw[cc];
    }
}

extern "C" void kernel_launch(void* const* d_in, const int* in_sizes, int n_in,
                              void* d_out, int out_size, void* d_ws, size_t ws_size,
                              hipStream_t stream) {
    const float* x      = (const float*)d_in[0];
    const float* in_w   = (const float*)d_in[1];
    const float* conv_w = (const float*)d_in[2];
    const float* conv_b = (const float*)d_in[3];
    const float* xp_w   = (const float*)d_in[4];
    const float* dt_w   = (const float*)d_in[5];
    const float* dt_b   = (const float*)d_in[6];
    const float* A_log  = (const float*)d_in[7];
    const float* D_skip = (const float*)d_in[8];
    const float* out_w  = (const float*)d_in[9];
    const float* rms_w  = (const float*)d_in[10];
    float* out = (float*)d_out;

    const int M = B_SZ * L_SEQ;   // 8192
    char* p = (char*)d_ws;
    auto alloc = [&](size_t bytes) -> void* {
        void* r = (void*)p; p += (bytes + 255) & ~(size_t)255; return r;
    };
    float* xz   = (float*)alloc((size_t)M * 512 * 4);
    float* xc   = (float*)alloc((size_t)M * DI * 4);
    float* xdbl = (float*)alloc((size_t)M * NXP * 4);
    float* hp0  = (float*)alloc((size_t)M * DIMC * 4);
    float* hp1  = (float*)alloc((size_t)M * DIMC * 4);
    float* paB  = (float*)alloc((size_t)B_SZ * NCH * DI * DST * 4);
    float* hB   = (float*)alloc((size_t)B_SZ * NCH * DI * DST * 4);
    unsigned short* hh0 = (unsigned short*)alloc((size_t)M * DIMC * 2);
    unsigned short* hl0 = (unsigned short*)alloc((size_t)M * DIMC * 2);
    unsigned short* hh1 = (unsigned short*)alloc((size_t)M * DIMC * 2);
    unsigned short* hl1 = (unsigned short*)alloc((size_t)M * DIMC * 2);
    unsigned short* xch = (unsigned short*)alloc((size_t)M * DI * 2);
    unsigned short* xcl = (unsigned short*)alloc((size_t)M * DI * 2);
    unsigned short* ybh = (unsigned short*)alloc((size_t)M * DI * 2);
    unsigned short* ybl = (unsigned short*)alloc((size_t)M * DI * 2);
    unsigned short* iwh = (unsigned short*)alloc((size_t)NLAYER * 512 * 128 * 2);
    unsigned short* iwl = (unsigned short*)alloc((size_t)NLAYER * 512 * 128 * 2);
    unsigned short* xpwh = (unsigned short*)alloc((size_t)NLAYER * NXP * DI * 2);
    unsigned short* xpwl = (unsigned short*)alloc((size_t)NLAYER * NXP * DI * 2);
    unsigned short* owh = (unsigned short*)alloc((size_t)NLAYER * DIMC * DI * 2);
    unsigned short* owl = (unsigned short*)alloc((size_t)NLAYER * DIMC * DI * 2);

    // weight splits (cheap, every call for determinism)
    split_arr<<<(NLAYER * 512 * 128) / 1024, 256, 0, stream>>>(in_w, iwh, iwl, NLAYER * 512 * 128);
    split_arr<<<(NLAYER * NXP * DI) / 1024, 256, 0, stream>>>(xp_w, xpwh, xpwl, NLAYER * NXP * DI);
    split_arr<<<(NLAYER * DIMC * DI) / 1024, 256, 0, stream>>>(out_w, owh, owl, NLAYER * DIMC * DI);

    // x (B,C,L) -> split bf16 (B,L,C)
    transpose_in<<<dim3(B_SZ, DIMC / 32, L_SEQ / 32), dim3(32, 8), 0, stream>>>(x, hh0, hl0);

    unsigned short *hhin = hh0, *hlin = hl0, *hhout = hh1, *hlout = hl1;
    float *hpin = hp0, *hpout = hp1;
    for (int layer = 0; layer < NLAYER; ++layer) {
        const float* cw  = conv_w + (size_t)layer * DI * 4;
        const float* cb  = conv_b + (size_t)layer * DI;
        const float* dtw = dt_w   + (size_t)layer * DI * DTR;
        const float* dtb = dt_b   + (size_t)layer * DI;
        const float* al  = A_log  + (size_t)layer * DI * DST;
        const float* ds  = D_skip + (size_t)layer * DI;
        const size_t iwo = (size_t)layer * 512 * 128;
        const size_t xpo = (size_t)layer * NXP * DI;
        const size_t owo = (size_t)layer * DIMC * DI;

        // in_proj: xz = h * in_w^T   (M x 512, K=128)
        gemm_sp<128, 128, false><<<dim3(M / 128, 4), 256, 0, stream>>>(
            hhin, hlin, iwh + iwo, iwl + iwo, xz, nullptr, nullptr, M, 512, 128);
        // conv + silu -> xc (+ split)
        conv_silu<<<(M * DI) / 256, 256, 0, stream>>>(xz, cw, cb, xc, xch, xcl);
        // x_proj: xdbl = xc * xp_w^T  (M x 40, K=256)
        gemm_sp<64, 64, false><<<dim3(M / 64, 1), 256, 0, stream>>>(
            xch, xcl, xpwh + xpo, xpwl + xpo, xdbl, nullptr, nullptr, M, NXP, DI);
        // chunked selective scan (dt fused) + gate -> yb split
        scan_chunkA<<<B_SZ * NCH, 256, 0, stream>>>(xdbl, xc, dtw, dtb, al, paB, hB);
        scan_combine<<<(B_SZ * DI * DST) / 256, 256, 0, stream>>>(paB, hB);
        scan_applyC<<<B_SZ * NCH, 256, 0, stream>>>(xdbl, xc, xz, dtw, dtb, al, ds, paB, ybh, ybl);
        // out_proj: h' = yb * out_w^T (M x 128, K=256), fp32 + split
        gemm_sp<64, 64, true><<<dim3(M / 64, 2), 256, 0, stream>>>(
            ybh, ybl, owh + owo, owl + owo, hpout, hhout, hlout, M, DIMC, DI);

        unsigned short* ts;
        ts = hhin; hhin = hhout; hhout = ts;
        ts = hlin; hlin = hlout; hlout = ts;
        float* tf = hpin; hpin = hpout; hpout = tf;
    }

    // RMSNorm + transpose to (B,C,H,W)
    rms_out<<<B_SZ * (L_SEQ / 64), 256, 0, stream>>>(hpin, rms_w, out);
}